// Round 14
// baseline (135.934 us; speedup 1.0000x reference)
//
#include <hip/hip_runtime.h>

#define DD 192
#define MAXD 96

typedef float f32x4 __attribute__((ext_vector_type(4)));
typedef unsigned int u32x4 __attribute__((ext_vector_type(4)));
typedef __fp16 h2 __attribute__((ext_vector_type(2)));
typedef __fp16 h8 __attribute__((ext_vector_type(8)));

static inline int ceil_div(int a, int b){ return (a + b - 1) / b; }
static inline size_t alignup(size_t x){ return (x + 511) & ~(size_t)511; }

static __device__ __forceinline__ h2 as_h2(unsigned u){ union{unsigned i; h2 h;} c; c.i=u; return c.h; }
static __device__ __forceinline__ unsigned as_u(h2 h){ union{h2 h; unsigned i;} c; c.h=h; return c.i; }

// DPP xor-add; RED8 sums within each 8-lane group: xor1, xor2, half-mirror.
#define DPPA(p, ctrl) do { \
    int _t = __builtin_amdgcn_update_dpp(0, __float_as_int(p), ctrl, 0xf, 0xf, true); \
    (p) += __int_as_float(_t); } while (0)
#define RED8(p)  do { DPPA(p,0xB1); DPPA(p,0x4E); DPPA(p,0x141); } while (0)

// ---------------------------------------------------------------------------
// K1: conv_w fp16+swizzle (blocks [0,convB)) ∥ deg zeroing (rest).
// ---------------------------------------------------------------------------
__global__ __launch_bounds__(256) void k1_conv_zero(
    const float* __restrict__ Wl, const float* __restrict__ Wr,
    __fp16* __restrict__ wcomb, int* __restrict__ deg, int N, int convB)
{
    const int b = blockIdx.x, t = threadIdx.x;
    if (b < convB) {
        int i = b * 256 + t;
        if (i >= DD * DD) return;
        int row = i / DD, k = i - row * DD;
        int j = row >> 4, r = row & 15;
        int sw = (r & 7) << 3;
        size_t base = (size_t)j * 6144;
        wcomb[base + ((      r * 192 + k) ^ sw)] = (__fp16)Wl[i];
        wcomb[base + (((16 + r) * 192 + k) ^ sw)] = (__fp16)Wr[i];
    } else {
        int i = (b - convB) * 256 + t;
        if (i < N) deg[i] = 0;
    }
}

// ---------------------------------------------------------------------------
// K2: proj via f16 MFMA, TWO 16-row M-tiles per wave (32 nodes/wave,
// 128/block) ∥ fused deg-histogram + adjacency scatter (colp stores
// src*384 byte offsets). B-frags feed 4 independent MFMA chains.
// ---------------------------------------------------------------------------
__global__ __launch_bounds__(256) void k2_proj_scatter(
    const float* __restrict__ x, const __fp16* __restrict__ wcomb,
    const float* __restrict__ bl, const float* __restrict__ br,
    __fp16* __restrict__ xlh, __fp16* __restrict__ xrh, int N,
    const int* __restrict__ ei, int* __restrict__ deg, int* __restrict__ colp,
    int E, int projB)
{
    __shared__ __fp16 wbuf[2][6144];    // 24 KB (proj branch only)
    const int t = threadIdx.x;

    if ((int)blockIdx.x >= projB) {
        int e0 = (((int)blockIdx.x - projB) * 256 + t) * 2;
        if (e0 < E) {                       // E even -> e0+1 < E too
            int2 s2 = *(const int2*)(ei + e0);
            int2 d2 = *(const int2*)(ei + E + e0);
            int p0 = atomicAdd(&deg[d2.x], 1);
            if (p0 < MAXD - 1) colp[d2.x * MAXD + p0] = s2.x * 384;
            int p1 = atomicAdd(&deg[d2.y], 1);
            if (p1 < MAXD - 1) colp[d2.y * MAXD + p1] = s2.y * 384;
        }
        return;
    }

    const int lane = t & 63;
    int n0 = blockIdx.x * 128 + (t >> 6) * 32;
    if (n0 > N - 32) n0 = N - 32;
    const int rr = lane & 15;
    const int kg = lane >> 4;
    const int sw = (rr & 7) << 3;

    const u32x4* wsrc = (const u32x4*)wcomb;   // slice j at j*768 units

    u32x4 st[3];
    #pragma unroll
    for (int q = 0; q < 3; ++q) st[q] = wsrc[q * 256 + t];

    // A fragments for both M-tiles (rows n0+rr and n0+16+rr)
    h8 ah0[6], ah1[6];
    {
        const float* xr0 = x + (size_t)(n0 + rr) * DD + kg * 8;
        const float* xr1 = x + (size_t)(n0 + 16 + rr) * DD + kg * 8;
        #pragma unroll
        for (int s = 0; s < 6; ++s) {
            f32x4 v0 = *(const f32x4*)(xr0 + 32 * s);
            f32x4 v1 = *(const f32x4*)(xr0 + 32 * s + 4);
            union { h2 p[4]; h8 v; } u;
            u.p[0] = __builtin_amdgcn_cvt_pkrtz(v0[0], v0[1]);
            u.p[1] = __builtin_amdgcn_cvt_pkrtz(v0[2], v0[3]);
            u.p[2] = __builtin_amdgcn_cvt_pkrtz(v1[0], v1[1]);
            u.p[3] = __builtin_amdgcn_cvt_pkrtz(v1[2], v1[3]);
            ah0[s] = u.v;
            f32x4 w0 = *(const f32x4*)(xr1 + 32 * s);
            f32x4 w1 = *(const f32x4*)(xr1 + 32 * s + 4);
            u.p[0] = __builtin_amdgcn_cvt_pkrtz(w0[0], w0[1]);
            u.p[1] = __builtin_amdgcn_cvt_pkrtz(w0[2], w0[3]);
            u.p[2] = __builtin_amdgcn_cvt_pkrtz(w1[0], w1[1]);
            u.p[3] = __builtin_amdgcn_cvt_pkrtz(w1[2], w1[3]);
            ah1[s] = u.v;
        }
    }

    #pragma unroll
    for (int q = 0; q < 3; ++q) ((u32x4*)wbuf[0])[q * 256 + t] = st[q];
    __syncthreads();

    #pragma unroll 1
    for (int j = 0; j < 12; ++j) {
        const int cb = j & 1;
        if (j < 11) {
            #pragma unroll
            for (int q = 0; q < 3; ++q)
                st[q] = wsrc[(size_t)(j + 1) * 768 + q * 256 + t];
        }

        f32x4 aL0 = {0.f,0.f,0.f,0.f}, aR0 = {0.f,0.f,0.f,0.f};
        f32x4 aL1 = {0.f,0.f,0.f,0.f}, aR1 = {0.f,0.f,0.f,0.f};
        const __fp16* wb = wbuf[cb];
        #pragma unroll
        for (int s = 0; s < 6; ++s) {
            const int ko = kg * 8 + 32 * s;
            h8 bL = *(const h8*)&wb[( rr       * 192 + ko) ^ sw];
            h8 bR = *(const h8*)&wb[((16 + rr) * 192 + ko) ^ sw];
            aL0 = __builtin_amdgcn_mfma_f32_16x16x32_f16(ah0[s], bL, aL0, 0, 0, 0);
            aR0 = __builtin_amdgcn_mfma_f32_16x16x32_f16(ah0[s], bR, aR0, 0, 0, 0);
            aL1 = __builtin_amdgcn_mfma_f32_16x16x32_f16(ah1[s], bL, aL1, 0, 0, 0);
            aR1 = __builtin_amdgcn_mfma_f32_16x16x32_f16(ah1[s], bR, aR1, 0, 0, 0);
        }

        if (j < 11) {
            #pragma unroll
            for (int q = 0; q < 3; ++q) ((u32x4*)wbuf[cb ^ 1])[q * 256 + t] = st[q];
        }

        const int col = 16 * j + rr;
        const float bcl = bl[col], bcr = br[col];
        #pragma unroll
        for (int r = 0; r < 4; ++r) {
            size_t o0 = (size_t)(n0 + kg * 4 + r) * DD + col;
            size_t o1 = (size_t)(n0 + 16 + kg * 4 + r) * DD + col;
            xlh[o0] = (__fp16)(aL0[r] + bcl);
            xrh[o0] = (__fp16)(aR0[r] + bcr);
            xlh[o1] = (__fp16)(aL1[r] + bcl);
            xrh[o1] = (__fp16)(aR1[r] + bcr);
        }
        __syncthreads();
    }
}

// ---------------------------------------------------------------------------
// Pull aggregation: one wave per dst node, 4 edges/iter (16 lanes/edge;
// lane owns dims 64s+4*l16..+3; each head = one 8-lane group -> RED8).
// colp holds src byte offsets (src*384). fp16 packed math; fused epilogue.
// ---------------------------------------------------------------------------
__global__ __launch_bounds__(256) void agg_kernel(
    const __fp16* __restrict__ xlh, const __fp16* __restrict__ xrh,
    const float* __restrict__ att,
    const float* __restrict__ x, const float* __restrict__ bias,
    const int* __restrict__ deg, const int* __restrict__ colp,
    float* __restrict__ out, int N)
{
    const int node = blockIdx.x * 4 + (threadIdx.x >> 6);
    if (node >= N) return;
    const int lane = threadIdx.x & 63;
    const int l16  = lane & 15;
    const int q    = lane >> 4;          // edge slot 0..3
    const float LOG2E = 1.4426950408889634f;

    h2 xr_[3][2], w6[3][2], w4[3][2];
    {
        const char* pr = (const char*)xrh + (size_t)node * 384 + 8 * l16;
        #pragma unroll
        for (int s = 0; s < 3; ++s) {
            uint2 u = *(const uint2*)(pr + 128 * s);
            xr_[s][0] = as_h2(u.x);
            xr_[s][1] = as_h2(u.y);
            f32x4 wv = *(const f32x4*)(att + 64 * s + 4 * l16);
            w6[s][0] = __builtin_amdgcn_cvt_pkrtz(0.6f * LOG2E * wv[0], 0.6f * LOG2E * wv[1]);
            w6[s][1] = __builtin_amdgcn_cvt_pkrtz(0.6f * LOG2E * wv[2], 0.6f * LOG2E * wv[3]);
            w4[s][0] = __builtin_amdgcn_cvt_pkrtz(0.4f * LOG2E * wv[0], 0.4f * LOG2E * wv[1]);
            w4[s][1] = __builtin_amdgcn_cvt_pkrtz(0.4f * LOG2E * wv[2], 0.4f * LOG2E * wv[3]);
        }
    }

    float acc[3][4] = {{0.f,0.f,0.f,0.f},{0.f,0.f,0.f,0.f},{0.f,0.f,0.f,0.f}};
    float den[3] = {0.f, 0.f, 0.f};

    const int dg    = min(deg[node], MAXD - 1);
    const int total = dg + 1;                 // self + edges
    const int base  = node * MAXD;
    const int self_off = node * 384;

    auto srcat = [&](int slot) -> int {       // returns xl byte offset
        bool v = slot < total;
        int cidx = base + ((v && slot > 0) ? slot - 1 : 0);
        int cv = colp[cidx];
        return (slot == 0 || !v) ? self_off : cv;
    };

    uint2 cur0, cur1, cur2, nxt0, nxt1, nxt2;
    {
        const char* pc = (const char*)xlh + srcat(q) + 8 * l16;
        cur0 = *(const uint2*)(pc);
        cur1 = *(const uint2*)(pc + 128);
        cur2 = *(const uint2*)(pc + 256);
    }
    int s_nxt = srcat(4 + q);

    for (int i = 0; i < total; i += 4) {
        int s_n2 = srcat(i + 8 + q);
        const char* pn = (const char*)xlh + s_nxt + 8 * l16;
        nxt0 = *(const uint2*)(pn);
        nxt1 = *(const uint2*)(pn + 128);
        nxt2 = *(const uint2*)(pn + 256);

        const bool vc = (i + q) < total;
        #pragma unroll
        for (int s = 0; s < 3; ++s) {
            const uint2 cu = (s == 0) ? cur0 : (s == 1) ? cur1 : cur2;
            h2 a0 = as_h2(cu.x), a1 = as_h2(cu.y);
            h2 u0 = a0 + xr_[s][0], u1 = a1 + xr_[s][1];
            h2 b0 = as_h2(as_u(u0) & 0x7FFF7FFFu);
            h2 b1 = as_h2(as_u(u1) & 0x7FFF7FFFu);
            float p = __builtin_amdgcn_fdot2(u0, w6[s][0], 0.f, false);
            p = __builtin_amdgcn_fdot2(b0, w4[s][0], p, false);
            p = __builtin_amdgcn_fdot2(u1, w6[s][1], p, false);
            p = __builtin_amdgcn_fdot2(b1, w4[s][1], p, false);
            RED8(p);
            p = vc ? p : -1e30f;
            float e = exp2f(p);
            den[s] += e;
            acc[s][0] = fmaf((float)a0.x, e, acc[s][0]);
            acc[s][1] = fmaf((float)a0.y, e, acc[s][1]);
            acc[s][2] = fmaf((float)a1.x, e, acc[s][2]);
            acc[s][3] = fmaf((float)a1.y, e, acc[s][3]);
        }
        cur0 = nxt0; cur1 = nxt1; cur2 = nxt2;
        s_nxt = s_n2;
    }

    // combine the four edge slots
    #pragma unroll
    for (int s = 0; s < 3; ++s) {
        den[s] += __shfl_xor(den[s], 16); den[s] += __shfl_xor(den[s], 32);
        #pragma unroll
        for (int j = 0; j < 4; ++j) {
            acc[s][j] += __shfl_xor(acc[s][j], 16);
            acc[s][j] += __shfl_xor(acc[s][j], 32);
        }
    }

    if (q == 0) {
        #pragma unroll
        for (int s = 0; s < 3; ++s) {
            float inv = __builtin_amdgcn_rcpf(den[s] + 1e-16f);
            f32x4 xv = *(const f32x4*)(x + (size_t)node * DD + 64 * s + 4 * l16);
            f32x4 bv = *(const f32x4*)(bias + 64 * s + 4 * l16);
            f32x4 o;
            #pragma unroll
            for (int j = 0; j < 4; ++j) {
                float v = fmaf(acc[s][j], inv, xv[j] + bv[j]);
                o[j] = v > 0.f ? v : 0.f;
            }
            *(f32x4*)(out + (size_t)node * DD + 64 * s + 4 * l16) = o;
        }
    }
}

extern "C" void kernel_launch(void* const* d_in, const int* in_sizes, int n_in,
                              void* d_out, int out_size, void* d_ws, size_t ws_size,
                              hipStream_t stream)
{
    const float* x    = (const float*)d_in[0];
    const float* Wl   = (const float*)d_in[1];
    const float* bl   = (const float*)d_in[2];
    const float* Wr   = (const float*)d_in[3];
    const float* br   = (const float*)d_in[4];
    const float* att  = (const float*)d_in[5];
    const float* bias = (const float*)d_in[6];
    const int*   ei   = (const int*)d_in[7];

    const int N = in_sizes[0] / DD;     // 50000
    const int E = in_sizes[7] / 2;      // 800000
    const int convB = ceil_div(DD * DD, 256);
    const int zeroB = ceil_div(N, 256);
    const int edgeB = ceil_div(E, 512); // 2 edges per thread
    const int projB = ceil_div(N, 128); // 32 nodes/wave, 128/block

    float* out = (float*)d_out;
    char*  ws  = (char*)d_ws;

    size_t off = 0;
    __fp16* xlh = (__fp16*)(ws + off); off = alignup(off + (size_t)N * DD * 2);
    __fp16* xrh = (__fp16*)(ws + off); off = alignup(off + (size_t)N * DD * 2);
    __fp16* wcomb = (__fp16*)(ws + off); off = alignup(off + (size_t)12 * 6144 * 2);
    int* deg  = (int*)(ws + off); off = alignup(off + (size_t)N * 4);
    int* colp = (int*)(ws + off); off = alignup(off + (size_t)N * MAXD * 4);

    k1_conv_zero<<<convB + zeroB, 256, 0, stream>>>(Wl, Wr, wcomb, deg, N, convB);
    k2_proj_scatter<<<projB + edgeB, 256, 0, stream>>>(x, wcomb, bl, br, xlh, xrh, N,
                                                       ei, deg, colp, E, projB);
    agg_kernel<<<ceil_div(N, 4), 256, 0, stream>>>(xlh, xrh, att, x, bias, deg, colp, out, N);
}

// Round 15
// 131.824 us; speedup vs baseline: 1.0312x; 1.0312x over previous
//
#include <hip/hip_runtime.h>

#define DD 192
#define MAXD 96

typedef float f32x4 __attribute__((ext_vector_type(4)));
typedef unsigned int u32x4 __attribute__((ext_vector_type(4)));
typedef __fp16 h2 __attribute__((ext_vector_type(2)));
typedef __fp16 h8 __attribute__((ext_vector_type(8)));

static inline int ceil_div(int a, int b){ return (a + b - 1) / b; }
static inline size_t alignup(size_t x){ return (x + 511) & ~(size_t)511; }

static __device__ __forceinline__ h2 as_h2(unsigned u){ union{unsigned i; h2 h;} c; c.i=u; return c.h; }
static __device__ __forceinline__ unsigned as_u(h2 h){ union{h2 h; unsigned i;} c; c.h=h; return c.i; }

// DPP xor-add; RED8 sums within each 8-lane group: xor1, xor2, half-mirror.
#define DPPA(p, ctrl) do { \
    int _t = __builtin_amdgcn_update_dpp(0, __float_as_int(p), ctrl, 0xf, 0xf, true); \
    (p) += __int_as_float(_t); } while (0)
#define RED8(p)  do { DPPA(p,0xB1); DPPA(p,0x4E); DPPA(p,0x141); } while (0)

// ---------------------------------------------------------------------------
// K1: conv_w fp16+swizzle (blocks [0,convB)) ∥ deg zeroing (rest).
// wcomb slice j: [{L,R} x 16 rows x 192 k] fp16, idx ^= (r&7)<<3, 12 KB.
// ---------------------------------------------------------------------------
__global__ __launch_bounds__(256) void k1_conv_zero(
    const float* __restrict__ Wl, const float* __restrict__ Wr,
    __fp16* __restrict__ wcomb, int* __restrict__ deg, int N, int convB)
{
    const int b = blockIdx.x, t = threadIdx.x;
    if (b < convB) {
        int i = b * 256 + t;
        if (i >= DD * DD) return;
        int row = i / DD, k = i - row * DD;
        int j = row >> 4, r = row & 15;
        int sw = (r & 7) << 3;
        size_t base = (size_t)j * 6144;
        wcomb[base + ((      r * 192 + k) ^ sw)] = (__fp16)Wl[i];
        wcomb[base + (((16 + r) * 192 + k) ^ sw)] = (__fp16)Wr[i];
    } else {
        int i = (b - convB) * 256 + t;
        if (i < N) deg[i] = 0;
    }
}

// ---------------------------------------------------------------------------
// K2: proj via f16 MFMA, 16 nodes/wave, 8 waves (512 thr, 128 nodes/block).
// W staged in TWO 72 KB phases (6 slices each): stage -> barrier ->
// 6 barrier-free col-tiles -> barrier -> restage (loads issued before the
// compute phase) -> barrier -> 6 more tiles. 3 barriers/block vs 24.
// ∥ fused deg-histogram + adjacency scatter (blocks [projB,...)).
// ---------------------------------------------------------------------------
__global__ __launch_bounds__(512) void k2_proj_scatter(
    const float* __restrict__ x, const __fp16* __restrict__ wcomb,
    const float* __restrict__ bl, const float* __restrict__ br,
    __fp16* __restrict__ xlh, __fp16* __restrict__ xrh, int N,
    const int* __restrict__ ei, int* __restrict__ deg, int* __restrict__ colp,
    int E, int projB)
{
    __shared__ __fp16 wbuf[36864];      // 72 KB = 6 slices
    const int t = threadIdx.x;

    if ((int)blockIdx.x >= projB) {
        int e0 = (((int)blockIdx.x - projB) * 512 + t) * 2;
        if (e0 < E) {                       // E even -> e0+1 < E too
            int2 s2 = *(const int2*)(ei + e0);
            int2 d2 = *(const int2*)(ei + E + e0);
            int p0 = atomicAdd(&deg[d2.x], 1);
            if (p0 < MAXD - 1) colp[d2.x * MAXD + p0] = s2.x * 384;
            int p1 = atomicAdd(&deg[d2.y], 1);
            if (p1 < MAXD - 1) colp[d2.y * MAXD + p1] = s2.y * 384;
        }
        return;
    }

    const int lane = t & 63;
    int n0 = blockIdx.x * 128 + (t >> 6) * 16;
    if (n0 > N - 16) n0 = N - 16;       // tail waves duplicate (benign)
    const int rr = lane & 15;
    const int kg = lane >> 4;
    const int sw = (rr & 7) << 3;

    const u32x4* wsrc = (const u32x4*)wcomb;   // 4608 units per 6-slice phase

    // stage phase A (slices 0..5): 9 x 16 B per thread, exact fit
    u32x4 st[9];
    #pragma unroll
    for (int q = 0; q < 9; ++q) st[q] = wsrc[q * 512 + t];

    // A fragments (convert hides staging latency)
    h8 ah[6];
    const float* xrow = x + (size_t)(n0 + rr) * DD + kg * 8;
    #pragma unroll
    for (int s = 0; s < 6; ++s) {
        f32x4 v0 = *(const f32x4*)(xrow + 32 * s);
        f32x4 v1 = *(const f32x4*)(xrow + 32 * s + 4);
        union { h2 p[4]; h8 v; } u;
        u.p[0] = __builtin_amdgcn_cvt_pkrtz(v0[0], v0[1]);
        u.p[1] = __builtin_amdgcn_cvt_pkrtz(v0[2], v0[3]);
        u.p[2] = __builtin_amdgcn_cvt_pkrtz(v1[0], v1[1]);
        u.p[3] = __builtin_amdgcn_cvt_pkrtz(v1[2], v1[3]);
        ah[s] = u.v;
    }

    #pragma unroll
    for (int q = 0; q < 9; ++q) ((u32x4*)wbuf)[q * 512 + t] = st[q];
    __syncthreads();

    // issue phase-B loads now; latency hides under phase-A compute
    #pragma unroll
    for (int q = 0; q < 9; ++q) st[q] = wsrc[4608 + q * 512 + t];

    auto tile = [&](int j, const __fp16* wb) {
        f32x4 aL = {0.f, 0.f, 0.f, 0.f};
        f32x4 aR = {0.f, 0.f, 0.f, 0.f};
        #pragma unroll
        for (int s = 0; s < 6; ++s) {
            const int ko = kg * 8 + 32 * s;
            h8 bL = *(const h8*)&wb[( rr       * 192 + ko) ^ sw];
            h8 bR = *(const h8*)&wb[((16 + rr) * 192 + ko) ^ sw];
            aL = __builtin_amdgcn_mfma_f32_16x16x32_f16(ah[s], bL, aL, 0, 0, 0);
            aR = __builtin_amdgcn_mfma_f32_16x16x32_f16(ah[s], bR, aR, 0, 0, 0);
        }
        const int col = 16 * j + rr;
        const float bcl = bl[col], bcr = br[col];
        #pragma unroll
        for (int r = 0; r < 4; ++r) {
            size_t o = (size_t)(n0 + kg * 4 + r) * DD + col;
            xlh[o] = (__fp16)(aL[r] + bcl);
            xrh[o] = (__fp16)(aR[r] + bcr);
        }
    };

    #pragma unroll
    for (int jj = 0; jj < 6; ++jj) tile(jj, wbuf + jj * 6144);

    __syncthreads();
    #pragma unroll
    for (int q = 0; q < 9; ++q) ((u32x4*)wbuf)[q * 512 + t] = st[q];
    __syncthreads();

    #pragma unroll
    for (int jj = 0; jj < 6; ++jj) tile(jj + 6, wbuf + jj * 6144);
}

// ---------------------------------------------------------------------------
// Pull aggregation: one wave per dst node, 4 edges/iter (16 lanes/edge;
// lane owns dims 64s+4*l16..+3; each head = one 8-lane group -> RED8).
// colp holds src byte offsets (src*384). fp16 packed math; fused epilogue.
// ---------------------------------------------------------------------------
__global__ __launch_bounds__(256) void agg_kernel(
    const __fp16* __restrict__ xlh, const __fp16* __restrict__ xrh,
    const float* __restrict__ att,
    const float* __restrict__ x, const float* __restrict__ bias,
    const int* __restrict__ deg, const int* __restrict__ colp,
    float* __restrict__ out, int N)
{
    const int node = blockIdx.x * 4 + (threadIdx.x >> 6);
    if (node >= N) return;
    const int lane = threadIdx.x & 63;
    const int l16  = lane & 15;
    const int q    = lane >> 4;          // edge slot 0..3
    const float LOG2E = 1.4426950408889634f;

    h2 xr_[3][2], w6[3][2], w4[3][2];
    {
        const char* pr = (const char*)xrh + (size_t)node * 384 + 8 * l16;
        #pragma unroll
        for (int s = 0; s < 3; ++s) {
            uint2 u = *(const uint2*)(pr + 128 * s);
            xr_[s][0] = as_h2(u.x);
            xr_[s][1] = as_h2(u.y);
            f32x4 wv = *(const f32x4*)(att + 64 * s + 4 * l16);
            w6[s][0] = __builtin_amdgcn_cvt_pkrtz(0.6f * LOG2E * wv[0], 0.6f * LOG2E * wv[1]);
            w6[s][1] = __builtin_amdgcn_cvt_pkrtz(0.6f * LOG2E * wv[2], 0.6f * LOG2E * wv[3]);
            w4[s][0] = __builtin_amdgcn_cvt_pkrtz(0.4f * LOG2E * wv[0], 0.4f * LOG2E * wv[1]);
            w4[s][1] = __builtin_amdgcn_cvt_pkrtz(0.4f * LOG2E * wv[2], 0.4f * LOG2E * wv[3]);
        }
    }

    float acc[3][4] = {{0.f,0.f,0.f,0.f},{0.f,0.f,0.f,0.f},{0.f,0.f,0.f,0.f}};
    float den[3] = {0.f, 0.f, 0.f};

    const int dg    = min(deg[node], MAXD - 1);
    const int total = dg + 1;                 // self + edges
    const int base  = node * MAXD;
    const int self_off = node * 384;

    auto srcat = [&](int slot) -> int {       // returns xl byte offset
        bool v = slot < total;
        int cidx = base + ((v && slot > 0) ? slot - 1 : 0);
        int cv = colp[cidx];
        return (slot == 0 || !v) ? self_off : cv;
    };

    uint2 cur0, cur1, cur2, nxt0, nxt1, nxt2;
    {
        const char* pc = (const char*)xlh + srcat(q) + 8 * l16;
        cur0 = *(const uint2*)(pc);
        cur1 = *(const uint2*)(pc + 128);
        cur2 = *(const uint2*)(pc + 256);
    }
    int s_nxt = srcat(4 + q);

    for (int i = 0; i < total; i += 4) {
        int s_n2 = srcat(i + 8 + q);
        const char* pn = (const char*)xlh + s_nxt + 8 * l16;
        nxt0 = *(const uint2*)(pn);
        nxt1 = *(const uint2*)(pn + 128);
        nxt2 = *(const uint2*)(pn + 256);

        const bool vc = (i + q) < total;
        #pragma unroll
        for (int s = 0; s < 3; ++s) {
            const uint2 cu = (s == 0) ? cur0 : (s == 1) ? cur1 : cur2;
            h2 a0 = as_h2(cu.x), a1 = as_h2(cu.y);
            h2 u0 = a0 + xr_[s][0], u1 = a1 + xr_[s][1];
            h2 b0 = as_h2(as_u(u0) & 0x7FFF7FFFu);
            h2 b1 = as_h2(as_u(u1) & 0x7FFF7FFFu);
            float p = __builtin_amdgcn_fdot2(u0, w6[s][0], 0.f, false);
            p = __builtin_amdgcn_fdot2(b0, w4[s][0], p, false);
            p = __builtin_amdgcn_fdot2(u1, w6[s][1], p, false);
            p = __builtin_amdgcn_fdot2(b1, w4[s][1], p, false);
            RED8(p);
            p = vc ? p : -1e30f;
            float e = exp2f(p);
            den[s] += e;
            acc[s][0] = fmaf((float)a0.x, e, acc[s][0]);
            acc[s][1] = fmaf((float)a0.y, e, acc[s][1]);
            acc[s][2] = fmaf((float)a1.x, e, acc[s][2]);
            acc[s][3] = fmaf((float)a1.y, e, acc[s][3]);
        }
        cur0 = nxt0; cur1 = nxt1; cur2 = nxt2;
        s_nxt = s_n2;
    }

    // combine the four edge slots
    #pragma unroll
    for (int s = 0; s < 3; ++s) {
        den[s] += __shfl_xor(den[s], 16); den[s] += __shfl_xor(den[s], 32);
        #pragma unroll
        for (int j = 0; j < 4; ++j) {
            acc[s][j] += __shfl_xor(acc[s][j], 16);
            acc[s][j] += __shfl_xor(acc[s][j], 32);
        }
    }

    if (q == 0) {
        #pragma unroll
        for (int s = 0; s < 3; ++s) {
            float inv = __builtin_amdgcn_rcpf(den[s] + 1e-16f);
            f32x4 xv = *(const f32x4*)(x + (size_t)node * DD + 64 * s + 4 * l16);
            f32x4 bv = *(const f32x4*)(bias + 64 * s + 4 * l16);
            f32x4 o;
            #pragma unroll
            for (int j = 0; j < 4; ++j) {
                float v = fmaf(acc[s][j], inv, xv[j] + bv[j]);
                o[j] = v > 0.f ? v : 0.f;
            }
            *(f32x4*)(out + (size_t)node * DD + 64 * s + 4 * l16) = o;
        }
    }
}

extern "C" void kernel_launch(void* const* d_in, const int* in_sizes, int n_in,
                              void* d_out, int out_size, void* d_ws, size_t ws_size,
                              hipStream_t stream)
{
    const float* x    = (const float*)d_in[0];
    const float* Wl   = (const float*)d_in[1];
    const float* bl   = (const float*)d_in[2];
    const float* Wr   = (const float*)d_in[3];
    const float* br   = (const float*)d_in[4];
    const float* att  = (const float*)d_in[5];
    const float* bias = (const float*)d_in[6];
    const int*   ei   = (const int*)d_in[7];

    const int N = in_sizes[0] / DD;     // 50000
    const int E = in_sizes[7] / 2;      // 800000
    const int convB = ceil_div(DD * DD, 256);
    const int zeroB = ceil_div(N, 256);
    const int edgeB = ceil_div(E, 1024); // 2 edges/thread, 512 threads
    const int projB = ceil_div(N, 128);  // 16 nodes/wave, 8 waves/block

    float* out = (float*)d_out;
    char*  ws  = (char*)d_ws;

    size_t off = 0;
    __fp16* xlh = (__fp16*)(ws + off); off = alignup(off + (size_t)N * DD * 2);
    __fp16* xrh = (__fp16*)(ws + off); off = alignup(off + (size_t)N * DD * 2);
    __fp16* wcomb = (__fp16*)(ws + off); off = alignup(off + (size_t)12 * 6144 * 2);
    int* deg  = (int*)(ws + off); off = alignup(off + (size_t)N * 4);
    int* colp = (int*)(ws + off); off = alignup(off + (size_t)N * MAXD * 4);

    k1_conv_zero<<<convB + zeroB, 256, 0, stream>>>(Wl, Wr, wcomb, deg, N, convB);
    k2_proj_scatter<<<projB + edgeB, 512, 0, stream>>>(x, wcomb, bl, br, xlh, xrh, N,
                                                       ei, deg, colp, E, projB);
    agg_kernel<<<ceil_div(N, 4), 256, 0, stream>>>(xlh, xrh, att, x, bias, deg, colp, out, N);
}

// Round 16
// 130.201 us; speedup vs baseline: 1.0440x; 1.0125x over previous
//
#include <hip/hip_runtime.h>

#define DD 192
#define MAXD 96

typedef float f32x4 __attribute__((ext_vector_type(4)));
typedef unsigned int u32x4 __attribute__((ext_vector_type(4)));
typedef __fp16 h2 __attribute__((ext_vector_type(2)));
typedef __fp16 h8 __attribute__((ext_vector_type(8)));

static inline int ceil_div(int a, int b){ return (a + b - 1) / b; }
static inline size_t alignup(size_t x){ return (x + 511) & ~(size_t)511; }

static __device__ __forceinline__ h2 as_h2(unsigned u){ union{unsigned i; h2 h;} c; c.i=u; return c.h; }
static __device__ __forceinline__ unsigned as_u(h2 h){ union{h2 h; unsigned i;} c; c.h=h; return c.i; }

// DPP xor-add; RED8 sums within each 8-lane group: xor1, xor2, half-mirror.
#define DPPA(p, ctrl) do { \
    int _t = __builtin_amdgcn_update_dpp(0, __float_as_int(p), ctrl, 0xf, 0xf, true); \
    (p) += __int_as_float(_t); } while (0)
#define RED8(p)  do { DPPA(p,0xB1); DPPA(p,0x4E); DPPA(p,0x141); } while (0)

// ---------------------------------------------------------------------------
// K1: conv_w fp16+swizzle (blocks [0,convB)) ∥ deg zeroing (rest).
// wcomb slice j: [{L,R} x 16 rows x 192 k] fp16, idx ^= (r&7)<<3, 12 KB.
// ---------------------------------------------------------------------------
__global__ __launch_bounds__(256) void k1_conv_zero(
    const float* __restrict__ Wl, const float* __restrict__ Wr,
    __fp16* __restrict__ wcomb, int* __restrict__ deg, int N, int convB)
{
    const int b = blockIdx.x, t = threadIdx.x;
    if (b < convB) {
        int i = b * 256 + t;
        if (i >= DD * DD) return;
        int row = i / DD, k = i - row * DD;
        int j = row >> 4, r = row & 15;
        int sw = (r & 7) << 3;
        size_t base = (size_t)j * 6144;
        wcomb[base + ((      r * 192 + k) ^ sw)] = (__fp16)Wl[i];
        wcomb[base + (((16 + r) * 192 + k) ^ sw)] = (__fp16)Wr[i];
    } else {
        int i = (b - convB) * 256 + t;
        if (i < N) deg[i] = 0;
    }
}

// ---------------------------------------------------------------------------
// K2: proj via single-pass f16 MFMA, 16 nodes/wave, 256-thr blocks, 24 KB
// double-buffered LDS (r13 structure) ∥ fused deg-histogram + adjacency
// scatter, 4 edges/thread (int4 loads, 4 independent atomic chains).
// colp stores src*384 byte offsets.
// ---------------------------------------------------------------------------
__global__ __launch_bounds__(256) void k2_proj_scatter(
    const float* __restrict__ x, const __fp16* __restrict__ wcomb,
    const float* __restrict__ bl, const float* __restrict__ br,
    __fp16* __restrict__ xlh, __fp16* __restrict__ xrh, int N,
    const int* __restrict__ ei, int* __restrict__ deg, int* __restrict__ colp,
    int E, int projB)
{
    __shared__ __fp16 wbuf[2][6144];    // 24 KB (proj branch only)
    const int t = threadIdx.x;

    if ((int)blockIdx.x >= projB) {
        int e0 = (((int)blockIdx.x - projB) * 256 + t) * 4;
        if (e0 + 3 < E) {
            int4 s4 = *(const int4*)(ei + e0);
            int4 d4 = *(const int4*)(ei + E + e0);
            int p0 = atomicAdd(&deg[d4.x], 1);
            if (p0 < MAXD - 1) colp[d4.x * MAXD + p0] = s4.x * 384;
            int p1 = atomicAdd(&deg[d4.y], 1);
            if (p1 < MAXD - 1) colp[d4.y * MAXD + p1] = s4.y * 384;
            int p2 = atomicAdd(&deg[d4.z], 1);
            if (p2 < MAXD - 1) colp[d4.z * MAXD + p2] = s4.z * 384;
            int p3 = atomicAdd(&deg[d4.w], 1);
            if (p3 < MAXD - 1) colp[d4.w * MAXD + p3] = s4.w * 384;
        } else {
            #pragma unroll
            for (int k = 0; k < 4; ++k) {
                int e = e0 + k;
                if (e < E) {
                    int s = ei[e], d = ei[E + e];
                    int p = atomicAdd(&deg[d], 1);
                    if (p < MAXD - 1) colp[d * MAXD + p] = s * 384;
                }
            }
        }
        return;
    }

    const int lane = t & 63;
    int n0 = blockIdx.x * 64 + (t >> 6) * 16;
    if (n0 > N - 16) n0 = N - 16;
    const int rr = lane & 15;
    const int kg = lane >> 4;
    const int sw = (rr & 7) << 3;

    const u32x4* wsrc = (const u32x4*)wcomb;   // slice j at j*768 units

    u32x4 st[3];
    #pragma unroll
    for (int q = 0; q < 3; ++q) st[q] = wsrc[q * 256 + t];

    h8 ah[6];
    const float* xrow = x + (size_t)(n0 + rr) * DD + kg * 8;
    #pragma unroll
    for (int s = 0; s < 6; ++s) {
        f32x4 v0 = *(const f32x4*)(xrow + 32 * s);
        f32x4 v1 = *(const f32x4*)(xrow + 32 * s + 4);
        union { h2 p[4]; h8 v; } u;
        u.p[0] = __builtin_amdgcn_cvt_pkrtz(v0[0], v0[1]);
        u.p[1] = __builtin_amdgcn_cvt_pkrtz(v0[2], v0[3]);
        u.p[2] = __builtin_amdgcn_cvt_pkrtz(v1[0], v1[1]);
        u.p[3] = __builtin_amdgcn_cvt_pkrtz(v1[2], v1[3]);
        ah[s] = u.v;
    }

    #pragma unroll
    for (int q = 0; q < 3; ++q) ((u32x4*)wbuf[0])[q * 256 + t] = st[q];
    __syncthreads();

    #pragma unroll 1
    for (int j = 0; j < 12; ++j) {
        const int cb = j & 1;
        if (j < 11) {
            #pragma unroll
            for (int q = 0; q < 3; ++q)
                st[q] = wsrc[(size_t)(j + 1) * 768 + q * 256 + t];
        }

        f32x4 aL = {0.f, 0.f, 0.f, 0.f};
        f32x4 aR = {0.f, 0.f, 0.f, 0.f};
        const __fp16* wb = wbuf[cb];
        #pragma unroll
        for (int s = 0; s < 6; ++s) {
            const int ko = kg * 8 + 32 * s;
            h8 bL = *(const h8*)&wb[( rr       * 192 + ko) ^ sw];
            h8 bR = *(const h8*)&wb[((16 + rr) * 192 + ko) ^ sw];
            aL = __builtin_amdgcn_mfma_f32_16x16x32_f16(ah[s], bL, aL, 0, 0, 0);
            aR = __builtin_amdgcn_mfma_f32_16x16x32_f16(ah[s], bR, aR, 0, 0, 0);
        }

        if (j < 11) {
            #pragma unroll
            for (int q = 0; q < 3; ++q) ((u32x4*)wbuf[cb ^ 1])[q * 256 + t] = st[q];
        }

        const int col = 16 * j + rr;
        const float bcl = bl[col], bcr = br[col];
        #pragma unroll
        for (int r = 0; r < 4; ++r) {
            size_t o = (size_t)(n0 + kg * 4 + r) * DD + col;
            xlh[o] = (__fp16)(aL[r] + bcl);
            xrh[o] = (__fp16)(aR[r] + bcr);
        }
        __syncthreads();
    }
}

// ---------------------------------------------------------------------------
// Pull aggregation: one wave per dst node, 4 edges/iter (16 lanes/edge;
// lane owns dims 64s+4*l16..+3; each head = one 8-lane group -> RED8).
// colp holds src byte offsets (src*384). fp16 packed math; fused epilogue.
// ---------------------------------------------------------------------------
__global__ __launch_bounds__(256) void agg_kernel(
    const __fp16* __restrict__ xlh, const __fp16* __restrict__ xrh,
    const float* __restrict__ att,
    const float* __restrict__ x, const float* __restrict__ bias,
    const int* __restrict__ deg, const int* __restrict__ colp,
    float* __restrict__ out, int N)
{
    const int node = blockIdx.x * 4 + (threadIdx.x >> 6);
    if (node >= N) return;
    const int lane = threadIdx.x & 63;
    const int l16  = lane & 15;
    const int q    = lane >> 4;          // edge slot 0..3
    const float LOG2E = 1.4426950408889634f;

    h2 xr_[3][2], w6[3][2], w4[3][2];
    {
        const char* pr = (const char*)xrh + (size_t)node * 384 + 8 * l16;
        #pragma unroll
        for (int s = 0; s < 3; ++s) {
            uint2 u = *(const uint2*)(pr + 128 * s);
            xr_[s][0] = as_h2(u.x);
            xr_[s][1] = as_h2(u.y);
            f32x4 wv = *(const f32x4*)(att + 64 * s + 4 * l16);
            w6[s][0] = __builtin_amdgcn_cvt_pkrtz(0.6f * LOG2E * wv[0], 0.6f * LOG2E * wv[1]);
            w6[s][1] = __builtin_amdgcn_cvt_pkrtz(0.6f * LOG2E * wv[2], 0.6f * LOG2E * wv[3]);
            w4[s][0] = __builtin_amdgcn_cvt_pkrtz(0.4f * LOG2E * wv[0], 0.4f * LOG2E * wv[1]);
            w4[s][1] = __builtin_amdgcn_cvt_pkrtz(0.4f * LOG2E * wv[2], 0.4f * LOG2E * wv[3]);
        }
    }

    float acc[3][4] = {{0.f,0.f,0.f,0.f},{0.f,0.f,0.f,0.f},{0.f,0.f,0.f,0.f}};
    float den[3] = {0.f, 0.f, 0.f};

    const int dg    = min(deg[node], MAXD - 1);
    const int total = dg + 1;                 // self + edges
    const int base  = node * MAXD;
    const int self_off = node * 384;

    auto srcat = [&](int slot) -> int {       // returns xl byte offset
        bool v = slot < total;
        int cidx = base + ((v && slot > 0) ? slot - 1 : 0);
        int cv = colp[cidx];
        return (slot == 0 || !v) ? self_off : cv;
    };

    uint2 cur0, cur1, cur2, nxt0, nxt1, nxt2;
    {
        const char* pc = (const char*)xlh + srcat(q) + 8 * l16;
        cur0 = *(const uint2*)(pc);
        cur1 = *(const uint2*)(pc + 128);
        cur2 = *(const uint2*)(pc + 256);
    }
    int s_nxt = srcat(4 + q);

    for (int i = 0; i < total; i += 4) {
        int s_n2 = srcat(i + 8 + q);
        const char* pn = (const char*)xlh + s_nxt + 8 * l16;
        nxt0 = *(const uint2*)(pn);
        nxt1 = *(const uint2*)(pn + 128);
        nxt2 = *(const uint2*)(pn + 256);

        const bool vc = (i + q) < total;
        #pragma unroll
        for (int s = 0; s < 3; ++s) {
            const uint2 cu = (s == 0) ? cur0 : (s == 1) ? cur1 : cur2;
            h2 a0 = as_h2(cu.x), a1 = as_h2(cu.y);
            h2 u0 = a0 + xr_[s][0], u1 = a1 + xr_[s][1];
            h2 b0 = as_h2(as_u(u0) & 0x7FFF7FFFu);
            h2 b1 = as_h2(as_u(u1) & 0x7FFF7FFFu);
            float p = __builtin_amdgcn_fdot2(u0, w6[s][0], 0.f, false);
            p = __builtin_amdgcn_fdot2(b0, w4[s][0], p, false);
            p = __builtin_amdgcn_fdot2(u1, w6[s][1], p, false);
            p = __builtin_amdgcn_fdot2(b1, w4[s][1], p, false);
            RED8(p);
            p = vc ? p : -1e30f;
            float e = exp2f(p);
            den[s] += e;
            acc[s][0] = fmaf((float)a0.x, e, acc[s][0]);
            acc[s][1] = fmaf((float)a0.y, e, acc[s][1]);
            acc[s][2] = fmaf((float)a1.x, e, acc[s][2]);
            acc[s][3] = fmaf((float)a1.y, e, acc[s][3]);
        }
        cur0 = nxt0; cur1 = nxt1; cur2 = nxt2;
        s_nxt = s_n2;
    }

    // combine the four edge slots
    #pragma unroll
    for (int s = 0; s < 3; ++s) {
        den[s] += __shfl_xor(den[s], 16); den[s] += __shfl_xor(den[s], 32);
        #pragma unroll
        for (int j = 0; j < 4; ++j) {
            acc[s][j] += __shfl_xor(acc[s][j], 16);
            acc[s][j] += __shfl_xor(acc[s][j], 32);
        }
    }

    if (q == 0) {
        #pragma unroll
        for (int s = 0; s < 3; ++s) {
            float inv = __builtin_amdgcn_rcpf(den[s] + 1e-16f);
            f32x4 xv = *(const f32x4*)(x + (size_t)node * DD + 64 * s + 4 * l16);
            f32x4 bv = *(const f32x4*)(bias + 64 * s + 4 * l16);
            f32x4 o;
            #pragma unroll
            for (int j = 0; j < 4; ++j) {
                float v = fmaf(acc[s][j], inv, xv[j] + bv[j]);
                o[j] = v > 0.f ? v : 0.f;
            }
            *(f32x4*)(out + (size_t)node * DD + 64 * s + 4 * l16) = o;
        }
    }
}

extern "C" void kernel_launch(void* const* d_in, const int* in_sizes, int n_in,
                              void* d_out, int out_size, void* d_ws, size_t ws_size,
                              hipStream_t stream)
{
    const float* x    = (const float*)d_in[0];
    const float* Wl   = (const float*)d_in[1];
    const float* bl   = (const float*)d_in[2];
    const float* Wr   = (const float*)d_in[3];
    const float* br   = (const float*)d_in[4];
    const float* att  = (const float*)d_in[5];
    const float* bias = (const float*)d_in[6];
    const int*   ei   = (const int*)d_in[7];

    const int N = in_sizes[0] / DD;     // 50000
    const int E = in_sizes[7] / 2;      // 800000
    const int convB = ceil_div(DD * DD, 256);
    const int zeroB = ceil_div(N, 256);
    const int edgeB = ceil_div(E, 1024); // 4 edges/thread, 256 threads
    const int projB = ceil_div(N, 64);   // 16 nodes/wave, 4 waves/block

    float* out = (float*)d_out;
    char*  ws  = (char*)d_ws;

    size_t off = 0;
    __fp16* xlh = (__fp16*)(ws + off); off = alignup(off + (size_t)N * DD * 2);
    __fp16* xrh = (__fp16*)(ws + off); off = alignup(off + (size_t)N * DD * 2);
    __fp16* wcomb = (__fp16*)(ws + off); off = alignup(off + (size_t)12 * 6144 * 2);
    int* deg  = (int*)(ws + off); off = alignup(off + (size_t)N * 4);
    int* colp = (int*)(ws + off); off = alignup(off + (size_t)N * MAXD * 4);

    k1_conv_zero<<<convB + zeroB, 256, 0, stream>>>(Wl, Wr, wcomb, deg, N, convB);
    k2_proj_scatter<<<projB + edgeB, 256, 0, stream>>>(x, wcomb, bl, br, xlh, xrh, N,
                                                       ei, deg, colp, E, projB);
    agg_kernel<<<ceil_div(N, 4), 256, 0, stream>>>(xlh, xrh, att, x, bias, deg, colp, out, N);
}

// Round 17
// 116.843 us; speedup vs baseline: 1.1634x; 1.1143x over previous
//
#include <hip/hip_runtime.h>

#define DD 192
#define MAXD 96

typedef float f32x4 __attribute__((ext_vector_type(4)));
typedef unsigned int u32x4 __attribute__((ext_vector_type(4)));
typedef __fp16 h2 __attribute__((ext_vector_type(2)));
typedef __fp16 h8 __attribute__((ext_vector_type(8)));

static inline int ceil_div(int a, int b){ return (a + b - 1) / b; }
static inline size_t alignup(size_t x){ return (x + 511) & ~(size_t)511; }

static __device__ __forceinline__ h2 as_h2(unsigned u){ union{unsigned i; h2 h;} c; c.i=u; return c.h; }
static __device__ __forceinline__ unsigned as_u(h2 h){ union{h2 h; unsigned i;} c; c.h=h; return c.i; }

// DPP xor-add; RED8 sums within each 8-lane group: xor1, xor2, half-mirror.
#define DPPA(p, ctrl) do { \
    int _t = __builtin_amdgcn_update_dpp(0, __float_as_int(p), ctrl, 0xf, 0xf, true); \
    (p) += __int_as_float(_t); } while (0)
#define RED8(p)  do { DPPA(p,0xB1); DPPA(p,0x4E); DPPA(p,0x141); } while (0)

// ---------------------------------------------------------------------------
// K1: conv_w fp16+swizzle (blocks [0,convB)) ∥ deg zeroing (rest).
// wcomb slice j: [{L,R} x 16 rows x 192 k] fp16, idx ^= (r&7)<<3, 12 KB.
// ---------------------------------------------------------------------------
__global__ __launch_bounds__(256) void k1_conv_zero(
    const float* __restrict__ Wl, const float* __restrict__ Wr,
    __fp16* __restrict__ wcomb, int* __restrict__ deg, int N, int convB)
{
    const int b = blockIdx.x, t = threadIdx.x;
    if (b < convB) {
        int i = b * 256 + t;
        if (i >= DD * DD) return;
        int row = i / DD, k = i - row * DD;
        int j = row >> 4, r = row & 15;
        int sw = (r & 7) << 3;
        size_t base = (size_t)j * 6144;
        wcomb[base + ((      r * 192 + k) ^ sw)] = (__fp16)Wl[i];
        wcomb[base + (((16 + r) * 192 + k) ^ sw)] = (__fp16)Wr[i];
    } else {
        int i = (b - convB) * 256 + t;
        if (i < N) deg[i] = 0;
    }
}

// ---------------------------------------------------------------------------
// K2: proj via single-pass f16 MFMA, 16 nodes/wave, 256-thr blocks, 24 KB
// double-buffered LDS ∥ fused deg-histogram + adjacency scatter,
// 2 edges/thread (r13-proven geometry). colp stores src*384 byte offsets.
// ---------------------------------------------------------------------------
__global__ __launch_bounds__(256) void k2_proj_scatter(
    const float* __restrict__ x, const __fp16* __restrict__ wcomb,
    const float* __restrict__ bl, const float* __restrict__ br,
    __fp16* __restrict__ xlh, __fp16* __restrict__ xrh, int N,
    const int* __restrict__ ei, int* __restrict__ deg, int* __restrict__ colp,
    int E, int projB)
{
    __shared__ __fp16 wbuf[2][6144];    // 24 KB (proj branch only)
    const int t = threadIdx.x;

    if ((int)blockIdx.x >= projB) {
        int e0 = (((int)blockIdx.x - projB) * 256 + t) * 2;
        if (e0 < E) {                       // E even -> e0+1 < E too
            int2 s2 = *(const int2*)(ei + e0);
            int2 d2 = *(const int2*)(ei + E + e0);
            int p0 = atomicAdd(&deg[d2.x], 1);
            if (p0 < MAXD - 1) colp[d2.x * MAXD + p0] = s2.x * 384;
            int p1 = atomicAdd(&deg[d2.y], 1);
            if (p1 < MAXD - 1) colp[d2.y * MAXD + p1] = s2.y * 384;
        }
        return;
    }

    const int lane = t & 63;
    int n0 = blockIdx.x * 64 + (t >> 6) * 16;
    if (n0 > N - 16) n0 = N - 16;
    const int rr = lane & 15;
    const int kg = lane >> 4;
    const int sw = (rr & 7) << 3;

    const u32x4* wsrc = (const u32x4*)wcomb;   // slice j at j*768 units

    u32x4 st[3];
    #pragma unroll
    for (int q = 0; q < 3; ++q) st[q] = wsrc[q * 256 + t];

    h8 ah[6];
    const float* xrow = x + (size_t)(n0 + rr) * DD + kg * 8;
    #pragma unroll
    for (int s = 0; s < 6; ++s) {
        f32x4 v0 = *(const f32x4*)(xrow + 32 * s);
        f32x4 v1 = *(const f32x4*)(xrow + 32 * s + 4);
        union { h2 p[4]; h8 v; } u;
        u.p[0] = __builtin_amdgcn_cvt_pkrtz(v0[0], v0[1]);
        u.p[1] = __builtin_amdgcn_cvt_pkrtz(v0[2], v0[3]);
        u.p[2] = __builtin_amdgcn_cvt_pkrtz(v1[0], v1[1]);
        u.p[3] = __builtin_amdgcn_cvt_pkrtz(v1[2], v1[3]);
        ah[s] = u.v;
    }

    #pragma unroll
    for (int q = 0; q < 3; ++q) ((u32x4*)wbuf[0])[q * 256 + t] = st[q];
    __syncthreads();

    #pragma unroll 1
    for (int j = 0; j < 12; ++j) {
        const int cb = j & 1;
        if (j < 11) {
            #pragma unroll
            for (int q = 0; q < 3; ++q)
                st[q] = wsrc[(size_t)(j + 1) * 768 + q * 256 + t];
        }

        f32x4 aL = {0.f, 0.f, 0.f, 0.f};
        f32x4 aR = {0.f, 0.f, 0.f, 0.f};
        const __fp16* wb = wbuf[cb];
        #pragma unroll
        for (int s = 0; s < 6; ++s) {
            const int ko = kg * 8 + 32 * s;
            h8 bL = *(const h8*)&wb[( rr       * 192 + ko) ^ sw];
            h8 bR = *(const h8*)&wb[((16 + rr) * 192 + ko) ^ sw];
            aL = __builtin_amdgcn_mfma_f32_16x16x32_f16(ah[s], bL, aL, 0, 0, 0);
            aR = __builtin_amdgcn_mfma_f32_16x16x32_f16(ah[s], bR, aR, 0, 0, 0);
        }

        if (j < 11) {
            #pragma unroll
            for (int q = 0; q < 3; ++q) ((u32x4*)wbuf[cb ^ 1])[q * 256 + t] = st[q];
        }

        const int col = 16 * j + rr;
        const float bcl = bl[col], bcr = br[col];
        #pragma unroll
        for (int r = 0; r < 4; ++r) {
            size_t o = (size_t)(n0 + kg * 4 + r) * DD + col;
            xlh[o] = (__fp16)(aL[r] + bcl);
            xrh[o] = (__fp16)(aR[r] + bcr);
        }
        __syncthreads();
    }
}

// ---------------------------------------------------------------------------
// Pull aggregation: one wave per dst node, 4 edges/iter (16 lanes/edge;
// lane owns dims 64s+4*l16..+3; each head = one 8-lane group -> RED8).
// colp holds src byte offsets (src*384). fp16 packed math; fused epilogue.
// ---------------------------------------------------------------------------
__global__ __launch_bounds__(256) void agg_kernel(
    const __fp16* __restrict__ xlh, const __fp16* __restrict__ xrh,
    const float* __restrict__ att,
    const float* __restrict__ x, const float* __restrict__ bias,
    const int* __restrict__ deg, const int* __restrict__ colp,
    float* __restrict__ out, int N)
{
    const int node = blockIdx.x * 4 + (threadIdx.x >> 6);
    if (node >= N) return;
    const int lane = threadIdx.x & 63;
    const int l16  = lane & 15;
    const int q    = lane >> 4;          // edge slot 0..3
    const float LOG2E = 1.4426950408889634f;

    h2 xr_[3][2], w6[3][2], w4[3][2];
    {
        const char* pr = (const char*)xrh + (size_t)node * 384 + 8 * l16;
        #pragma unroll
        for (int s = 0; s < 3; ++s) {
            uint2 u = *(const uint2*)(pr + 128 * s);
            xr_[s][0] = as_h2(u.x);
            xr_[s][1] = as_h2(u.y);
            f32x4 wv = *(const f32x4*)(att + 64 * s + 4 * l16);
            w6[s][0] = __builtin_amdgcn_cvt_pkrtz(0.6f * LOG2E * wv[0], 0.6f * LOG2E * wv[1]);
            w6[s][1] = __builtin_amdgcn_cvt_pkrtz(0.6f * LOG2E * wv[2], 0.6f * LOG2E * wv[3]);
            w4[s][0] = __builtin_amdgcn_cvt_pkrtz(0.4f * LOG2E * wv[0], 0.4f * LOG2E * wv[1]);
            w4[s][1] = __builtin_amdgcn_cvt_pkrtz(0.4f * LOG2E * wv[2], 0.4f * LOG2E * wv[3]);
        }
    }

    float acc[3][4] = {{0.f,0.f,0.f,0.f},{0.f,0.f,0.f,0.f},{0.f,0.f,0.f,0.f}};
    float den[3] = {0.f, 0.f, 0.f};

    const int dg    = min(deg[node], MAXD - 1);
    const int total = dg + 1;                 // self + edges
    const int base  = node * MAXD;
    const int self_off = node * 384;

    auto srcat = [&](int slot) -> int {       // returns xl byte offset
        bool v = slot < total;
        int cidx = base + ((v && slot > 0) ? slot - 1 : 0);
        int cv = colp[cidx];
        return (slot == 0 || !v) ? self_off : cv;
    };

    uint2 cur0, cur1, cur2, nxt0, nxt1, nxt2;
    {
        const char* pc = (const char*)xlh + srcat(q) + 8 * l16;
        cur0 = *(const uint2*)(pc);
        cur1 = *(const uint2*)(pc + 128);
        cur2 = *(const uint2*)(pc + 256);
    }
    int s_nxt = srcat(4 + q);

    for (int i = 0; i < total; i += 4) {
        int s_n2 = srcat(i + 8 + q);
        const char* pn = (const char*)xlh + s_nxt + 8 * l16;
        nxt0 = *(const uint2*)(pn);
        nxt1 = *(const uint2*)(pn + 128);
        nxt2 = *(const uint2*)(pn + 256);

        const bool vc = (i + q) < total;
        #pragma unroll
        for (int s = 0; s < 3; ++s) {
            const uint2 cu = (s == 0) ? cur0 : (s == 1) ? cur1 : cur2;
            h2 a0 = as_h2(cu.x), a1 = as_h2(cu.y);
            h2 u0 = a0 + xr_[s][0], u1 = a1 + xr_[s][1];
            h2 b0 = as_h2(as_u(u0) & 0x7FFF7FFFu);
            h2 b1 = as_h2(as_u(u1) & 0x7FFF7FFFu);
            float p = __builtin_amdgcn_fdot2(u0, w6[s][0], 0.f, false);
            p = __builtin_amdgcn_fdot2(b0, w4[s][0], p, false);
            p = __builtin_amdgcn_fdot2(u1, w6[s][1], p, false);
            p = __builtin_amdgcn_fdot2(b1, w4[s][1], p, false);
            RED8(p);
            p = vc ? p : -1e30f;
            float e = exp2f(p);
            den[s] += e;
            acc[s][0] = fmaf((float)a0.x, e, acc[s][0]);
            acc[s][1] = fmaf((float)a0.y, e, acc[s][1]);
            acc[s][2] = fmaf((float)a1.x, e, acc[s][2]);
            acc[s][3] = fmaf((float)a1.y, e, acc[s][3]);
        }
        cur0 = nxt0; cur1 = nxt1; cur2 = nxt2;
        s_nxt = s_n2;
    }

    // combine the four edge slots
    #pragma unroll
    for (int s = 0; s < 3; ++s) {
        den[s] += __shfl_xor(den[s], 16); den[s] += __shfl_xor(den[s], 32);
        #pragma unroll
        for (int j = 0; j < 4; ++j) {
            acc[s][j] += __shfl_xor(acc[s][j], 16);
            acc[s][j] += __shfl_xor(acc[s][j], 32);
        }
    }

    if (q == 0) {
        #pragma unroll
        for (int s = 0; s < 3; ++s) {
            float inv = __builtin_amdgcn_rcpf(den[s] + 1e-16f);
            f32x4 xv = *(const f32x4*)(x + (size_t)node * DD + 64 * s + 4 * l16);
            f32x4 bv = *(const f32x4*)(bias + 64 * s + 4 * l16);
            f32x4 o;
            #pragma unroll
            for (int j = 0; j < 4; ++j) {
                float v = fmaf(acc[s][j], inv, xv[j] + bv[j]);
                o[j] = v > 0.f ? v : 0.f;
            }
            *(f32x4*)(out + (size_t)node * DD + 64 * s + 4 * l16) = o;
        }
    }
}

extern "C" void kernel_launch(void* const* d_in, const int* in_sizes, int n_in,
                              void* d_out, int out_size, void* d_ws, size_t ws_size,
                              hipStream_t stream)
{
    const float* x    = (const float*)d_in[0];
    const float* Wl   = (const float*)d_in[1];
    const float* bl   = (const float*)d_in[2];
    const float* Wr   = (const float*)d_in[3];
    const float* br   = (const float*)d_in[4];
    const float* att  = (const float*)d_in[5];
    const float* bias = (const float*)d_in[6];
    const int*   ei   = (const int*)d_in[7];

    const int N = in_sizes[0] / DD;     // 50000
    const int E = in_sizes[7] / 2;      // 800000
    const int convB = ceil_div(DD * DD, 256);
    const int zeroB = ceil_div(N, 256);
    const int edgeB = ceil_div(E, 512); // 2 edges/thread, 256 threads
    const int projB = ceil_div(N, 64);  // 16 nodes/wave, 4 waves/block

    float* out = (float*)d_out;
    char*  ws  = (char*)d_ws;

    size_t off = 0;
    __fp16* xlh = (__fp16*)(ws + off); off = alignup(off + (size_t)N * DD * 2);
    __fp16* xrh = (__fp16*)(ws + off); off = alignup(off + (size_t)N * DD * 2);
    __fp16* wcomb = (__fp16*)(ws + off); off = alignup(off + (size_t)12 * 6144 * 2);
    int* deg  = (int*)(ws + off); off = alignup(off + (size_t)N * 4);
    int* colp = (int*)(ws + off); off = alignup(off + (size_t)N * MAXD * 4);

    k1_conv_zero<<<convB + zeroB, 256, 0, stream>>>(Wl, Wr, wcomb, deg, N, convB);
    k2_proj_scatter<<<projB + edgeB, 256, 0, stream>>>(x, wcomb, bl, br, xlh, xrh, N,
                                                       ei, deg, colp, E, projB);
    agg_kernel<<<ceil_div(N, 4), 256, 0, stream>>>(xlh, xrh, att, x, bias, deg, colp, out, N);
}